// Round 3
// baseline (154.608 us; speedup 1.0000x reference)
//
#include <hip/hip_runtime.h>

#define NN  50000
#define DEG 32
#define DF  128
#define DO  256
#define FEAT4 (NN * DF / 4)   // 1,600,000 float4 groups

typedef __bf16 bf16x8 __attribute__((ext_vector_type(8)));
typedef float  f32x4  __attribute__((ext_vector_type(4)));
typedef float  f32x2  __attribute__((ext_vector_type(2)));
typedef unsigned short u16x8 __attribute__((ext_vector_type(8)));

#if defined(__has_builtin)
#if __has_builtin(__builtin_amdgcn_cvt_pk_f32_fp8) && __has_builtin(__builtin_amdgcn_cvt_pk_fp8_f32)
#define HW_FP8 1
#endif
#endif
#ifndef HW_FP8
#define HW_FP8 0
#endif

__device__ __forceinline__ unsigned short f2bf(float f) {
    unsigned u = __float_as_uint(f);
    u += 0x7FFF + ((u >> 16) & 1);     // round-to-nearest-even
    return (unsigned short)(u >> 16);
}

#if !HW_FP8
__device__ __forceinline__ unsigned enc1_fp8(float f) {
    unsigned u = __float_as_uint(f);
    unsigned s = (u >> 31) << 7;
    float a = fabsf(f);
    if (!(a > 0.f)) return s;
    if (a >= 448.f) return s | 0x7E;
    u = __float_as_uint(a);
    int e = (int)((u >> 23) & 255) - 127;
    if (e < -6) {
        unsigned m = (unsigned)(a * 512.f + 0.5f);
        if (m >= 8) return s | 0x08;
        return s | m;
    }
    unsigned mant = (u >> 20) & 7;
    unsigned rnd  = ((u >> 19) & 1) & (((u & 0x7FFFF) != 0) | ((u >> 20) & 1));
    unsigned enc  = ((unsigned)(e + 7) << 3) | mant;
    return s | (enc + rnd);
}
__device__ __forceinline__ float dec1_fp8(unsigned b) {
    unsigned s = (b >> 7) & 1, e = (b >> 3) & 15, m = b & 7;
    float v = (e == 0) ? (float)m * 0.001953125f
                       : __uint_as_float(((e - 7 + 127) << 23) | (m << 20));
    return s ? -v : v;
}
#endif

__device__ __forceinline__ unsigned enc4_fp8(float4 v) {
#if HW_FP8
    int pk = 0;
    pk = __builtin_amdgcn_cvt_pk_fp8_f32(v.x, v.y, pk, false);
    pk = __builtin_amdgcn_cvt_pk_fp8_f32(v.z, v.w, pk, true);
    return (unsigned)pk;
#else
    return enc1_fp8(v.x) | (enc1_fp8(v.y) << 8) | (enc1_fp8(v.z) << 16) | (enc1_fp8(v.w) << 24);
#endif
}

// ---------------------------------------------------------------------------
// Convert: feat fp32 -> fp8 e4m3 gather table;  W fp32 [K][N] -> Wt bf16 [N][K].
// ---------------------------------------------------------------------------
__global__ __launch_bounds__(256) void convert_kernel(
    const float* __restrict__ feat, const float* __restrict__ W,
    unsigned* __restrict__ feat8, unsigned short* __restrict__ Wt)
{
    const int gid = blockIdx.x * 256 + threadIdx.x;
    if (gid < FEAT4) {
        const float4 v = ((const float4*)feat)[gid];
        feat8[gid] = enc4_fp8(v);
    } else {
        const int t = gid - FEAT4;
        if (t < DO * DO) {
            const int n = t >> 8, k = t & 255;
            Wt[n * DO + k] = f2bf(W[k * DO + n]);   // write coalesced along k
        }
    }
}

// ---------------------------------------------------------------------------
// Fused aggregation + GEMM, latency-hiding restructure (R3):
//  BM=32 nodes, BN=256 per block, 512 threads (8 waves, 1x8), 1563 blocks.
//  - 1 node per 16-lane group (full gather TLP, no serial 2-pass)
//  - all 32 gather loads ISSUED before kc=0 staging; the barrier's vmcnt
//    drain overlaps gather latency with staging loads (T14 issue-early)
//  - accumulation (VALU) placed after kc=0 MFMA
//  - LDT=68: 39.2 KB LDS -> 4 blocks/CU (32 waves, occupancy cap) and
//    bank-stride 34 -> fragment reads hit banks 2r (conflict-free)
// ---------------------------------------------------------------------------
#define BM  32
#define BN  256
#define LDT 68

__global__ __launch_bounds__(512) void fused_kernel(
    const float*          __restrict__ feat,
    const unsigned*       __restrict__ feat8,
    const int*            __restrict__ edges,
    const unsigned short* __restrict__ Wt,
    float*                __restrict__ out)
{
    __shared__ __align__(16) unsigned short Asw[BM * LDT];
    __shared__ __align__(16) unsigned short Bsw[BN * LDT];

    const int tid = threadIdx.x;
    const int m0  = blockIdx.x * BM;
    const int l   = tid & 15;          // 16 lanes per node, lane owns cols [8l,8l+8)
    const int rn  = tid >> 4;          // node row 0..31

    int gnode = m0 + rn;
    if (gnode >= NN) gnode = NN - 1;

    // ---- issue all gather loads up front (stay in flight through staging)
    const int4* e4 = (const int4*)(edges + (size_t)gnode * DEG);
    int4 eidx[8];
    #pragma unroll
    for (int j = 0; j < 8; ++j) eidx[j] = e4[j];
    uint2 pk[DEG];
    #pragma unroll
    for (int j = 0; j < 8; ++j) {
        pk[4 * j + 0] = *(const uint2*)(feat8 + (size_t)eidx[j].x * (DF / 4) + l * 2);
        pk[4 * j + 1] = *(const uint2*)(feat8 + (size_t)eidx[j].y * (DF / 4) + l * 2);
        pk[4 * j + 2] = *(const uint2*)(feat8 + (size_t)eidx[j].z * (DF / 4) + l * 2);
        pk[4 * j + 3] = *(const uint2*)(feat8 + (size_t)eidx[j].w * (DF / 4) + l * 2);
    }

    // ---- GEMM setup
    const int wave = tid >> 6, lane = tid & 63;
    const int quad = lane >> 4, lr = lane & 15;
    const int wn   = wave * 32;

    u16x8 aggr;
    f32x4 acc[2][2] = {};

    for (int kc = 0; kc < 4; ++kc) {
        if (kc) __syncthreads();       // protect LDS overwrite

        if (kc < 2) {
            // A chunk from fp32 self features: 32 rows x 64 cols, float4/thread
            const int c = (tid & 15) * 4;      // col 0..60 step 4
            const float4 v = *(const float4*)(feat + (size_t)gnode * DF + kc * 64 + c);
            ushort4 o;
            o.x = f2bf(v.x); o.y = f2bf(v.y); o.z = f2bf(v.z); o.w = f2bf(v.w);
            *(ushort4*)(Asw + rn * LDT + c) = o;
        } else if ((l >> 3) == (kc - 2)) {
            // A chunk from agg registers (kc=2: lanes l<8 -> cols 0..63;
            //                             kc=3: lanes l>=8 -> cols 64..127)
            const int c = (l & 7) * 8;
            *(u16x8*)(Asw + rn * LDT + c) = aggr;
        }

        // B chunk: 256 rows x 64 cols from Wt (L2-resident), 4 segs/thread
        #pragma unroll
        for (int it = 0; it < 4; ++it) {
            const int sidx = it * 512 + tid;
            const int r = sidx >> 3;
            const int c = (sidx & 7) * 8;
            *(u16x8*)(Bsw + r * LDT + c) =
                *(const u16x8*)(Wt + (size_t)r * DO + kc * 64 + c);
        }

        __syncthreads();

        #pragma unroll
        for (int kk = 0; kk < 64; kk += 32) {
            bf16x8 af[2], bfr[2];
            #pragma unroll
            for (int i = 0; i < 2; ++i)
                af[i] = *(const bf16x8*)(Asw + (i * 16 + lr) * LDT + kk + quad * 8);
            #pragma unroll
            for (int i = 0; i < 2; ++i)
                bfr[i] = *(const bf16x8*)(Bsw + (wn + i * 16 + lr) * LDT + kk + quad * 8);
            #pragma unroll
            for (int mi = 0; mi < 2; ++mi)
                #pragma unroll
                for (int ni = 0; ni < 2; ++ni)
                    acc[mi][ni] = __builtin_amdgcn_mfma_f32_16x16x32_bf16(
                        af[mi], bfr[ni], acc[mi][ni], 0, 0, 0);
        }

        if (kc == 0) {
            // ---- accumulate the (already-drained) gather data; pure VALU,
            //      overlaps other waves' MFMA. Result needed first at kc=2.
            float a[8] = {0.f, 0.f, 0.f, 0.f, 0.f, 0.f, 0.f, 0.f};
            #pragma unroll
            for (int d = 0; d < DEG; ++d) {
#if HW_FP8
                const f32x2 v0 = __builtin_amdgcn_cvt_pk_f32_fp8((int)pk[d].x, false);
                const f32x2 v1 = __builtin_amdgcn_cvt_pk_f32_fp8((int)pk[d].x, true);
                const f32x2 v2 = __builtin_amdgcn_cvt_pk_f32_fp8((int)pk[d].y, false);
                const f32x2 v3 = __builtin_amdgcn_cvt_pk_f32_fp8((int)pk[d].y, true);
                a[0] += v0[0]; a[1] += v0[1]; a[2] += v1[0]; a[3] += v1[1];
                a[4] += v2[0]; a[5] += v2[1]; a[6] += v3[0]; a[7] += v3[1];
#else
                #pragma unroll
                for (int j = 0; j < 4; ++j) a[j]     += dec1_fp8((pk[d].x >> (8 * j)) & 255);
                #pragma unroll
                for (int j = 0; j < 4; ++j) a[4 + j] += dec1_fp8((pk[d].y >> (8 * j)) & 255);
#endif
            }
            const float s = 1.0f / (float)DEG;
            #pragma unroll
            for (int j = 0; j < 8; ++j) aggr[j] = f2bf(a[j] * s);
        }
    }

    // ---- epilogue: relu + store
    #pragma unroll
    for (int mi = 0; mi < 2; ++mi) {
        #pragma unroll
        for (int r = 0; r < 4; ++r) {
            const int row = m0 + mi * 16 + quad * 4 + r;
            if (row < NN) {
                #pragma unroll
                for (int ni = 0; ni < 2; ++ni) {
                    out[(size_t)row * DO + wn + ni * 16 + lr] =
                        fmaxf(acc[mi][ni][r], 0.f);
                }
            }
        }
    }
}

extern "C" void kernel_launch(void* const* d_in, const int* in_sizes, int n_in,
                              void* d_out, int out_size, void* d_ws, size_t ws_size,
                              hipStream_t stream)
{
    const float* feat  = (const float*)d_in[0];
    const int*   edges = (const int*)d_in[1];
    const float* W     = (const float*)d_in[2];
    float*       out   = (float*)d_out;

    unsigned*       feat8 = (unsigned*)d_ws;                          // 6.4 MB
    unsigned short* Wt    = (unsigned short*)(feat8 + (size_t)NN * DF / 4); // 128 KB

    convert_kernel<<<(FEAT4 + DO * DO + 255) / 256, 256, 0, stream>>>(
        feat, W, feat8, Wt);

    fused_kernel<<<(NN + BM - 1) / BM, 512, 0, stream>>>(
        feat, feat8, edges, Wt, out);
}